// Round 2
// baseline (385.407 us; speedup 1.0000x reference)
//
#include <hip/hip_runtime.h>

// Geometry constants
// x:   (128, 128, 56, 56) f32     c = 2*k + i2
// w1:  (64, 3, 4) f32             w1[k, tap, j4]
// w2:  (2, 3, 32) f32             w2[i2, tap, j]
// t4:  (128, 8, 3136) f32 in ws   [l][(i2*4+j4)][m*56+o]
// out: (128, 128, 56, 56) f32     out[l][j*4+o4][m][n]
//
// Stage 1: t4[l,i2,m,o,j4] = sum_{k,tap} xroll[l,2k+i2, m+tap-1, o] * w1[k,tap,j4]
//   where xroll[...,h,o] = x[...,(h-1)%56,o] (roll +1 along H), zero-pad h<0 or h>55.
//   => row = (h==0) ? 55 : h-1, valid iff 0<=h<=55.
// Stage 2: out[l, j*4+o4, m, n] = sum_{i2,k} t4[l,i2,m,n+k-1,o4] * w2[i2,k,j]
//   zero-pad n+k-1 outside [0,55].

__global__ __launch_bounds__(448) void stage1_kernel(
    const float* __restrict__ x, const float* __restrict__ w1,
    float* __restrict__ t4)
{
    const int l = blockIdx.x / 7;
    const int p = (blockIdx.x % 7) * 448 + threadIdx.x;   // p in [0,3136)
    const int m = p / 56;
    const int o = p - m * 56;

    int   off[3];
    bool  valid[3];
#pragma unroll
    for (int t = 0; t < 3; ++t) {
        const int h = m + t - 1;              // row of rolled tensor
        valid[t] = (h >= 0) && (h < 56);
        const int row = (h <= 0) ? 55 : (h - 1);  // roll(+1): h==0 -> src row 55
        off[t] = row * 56 + o;                // safe in-bounds even when invalid
    }

    float acc[2][4];
#pragma unroll
    for (int i2 = 0; i2 < 2; ++i2)
#pragma unroll
        for (int j = 0; j < 4; ++j) acc[i2][j] = 0.0f;

    const float* xl = x + (size_t)l * 128 * 3136;

    for (int k = 0; k < 64; ++k) {
        float w[3][4];                        // uniform indices -> s_load
#pragma unroll
        for (int t = 0; t < 3; ++t)
#pragma unroll
            for (int j = 0; j < 4; ++j)
                w[t][j] = w1[(k * 3 + t) * 4 + j];

#pragma unroll
        for (int i2 = 0; i2 < 2; ++i2) {
            const float* xc = xl + (size_t)(2 * k + i2) * 3136;
#pragma unroll
            for (int t = 0; t < 3; ++t) {
                const float xv = valid[t] ? xc[off[t]] : 0.0f;
#pragma unroll
                for (int j = 0; j < 4; ++j)
                    acc[i2][j] = fmaf(xv, w[t][j], acc[i2][j]);
            }
        }
    }

    float* t4l = t4 + (size_t)l * 8 * 3136 + p;
#pragma unroll
    for (int i2 = 0; i2 < 2; ++i2)
#pragma unroll
        for (int j = 0; j < 4; ++j)
            t4l[(size_t)(i2 * 4 + j) * 3136] = acc[i2][j];
}

__global__ __launch_bounds__(256) void stage2_kernel(
    const float* __restrict__ t4, const float* __restrict__ w2,
    float* __restrict__ out)
{
    const int l = blockIdx.x / 56;
    const int m = blockIdx.x % 56;

    __shared__ float lds[8 * 58];             // [io][1+n'], zero pad at 0 and 57
    const int tid = threadIdx.x;

    if (tid < 16) lds[(tid >> 1) * 58 + (tid & 1) * 57] = 0.0f;
    // 448 tile elements staged by 256 threads (2 rounds; was the round-1 bug)
    for (int t = tid; t < 448; t += 256) {
        const int io = t / 56;
        const int np = t - io * 56;
        lds[io * 58 + 1 + np] =
            t4[((size_t)l * 8 + io) * 3136 + m * 56 + np];
    }
    __syncthreads();

    const int n  = tid & 63;                  // lane = n (W position)
    const int o4 = tid >> 6;                  // wave id = o4 in [0,4)
    if (n >= 56) return;

    float v[2][3];                            // t4[l, i2, m, n+k-1, o4]
#pragma unroll
    for (int i = 0; i < 2; ++i)
#pragma unroll
        for (int k = 0; k < 3; ++k)
            v[i][k] = lds[(i * 4 + o4) * 58 + n + k];

    float* ob = out + (((size_t)l * 128 + o4) * 56 + m) * 56 + n;

#pragma unroll
    for (int j = 0; j < 32; ++j) {            // compile-time w2 indices -> s_load
        float s = 0.0f;
#pragma unroll
        for (int i = 0; i < 2; ++i)
#pragma unroll
            for (int k = 0; k < 3; ++k)
                s = fmaf(v[i][k], w2[(i * 3 + k) * 32 + j], s);
        ob[(size_t)(j * 4) * 3136] = s;       // c = j*4 + o4
    }
}

extern "C" void kernel_launch(void* const* d_in, const int* in_sizes, int n_in,
                              void* d_out, int out_size, void* d_ws, size_t ws_size,
                              hipStream_t stream)
{
    const float* x  = (const float*)d_in[0];
    const float* w1 = (const float*)d_in[1];
    const float* w2 = (const float*)d_in[2];
    float* out = (float*)d_out;
    float* t4  = (float*)d_ws;                // 128*8*3136*4 = 12.8 MB

    stage1_kernel<<<dim3(128 * 7), dim3(448), 0, stream>>>(x, w1, t4);
    stage2_kernel<<<dim3(128 * 56), dim3(256), 0, stream>>>(t4, w2, out);
}